// Round 6
// baseline (725.564 us; speedup 1.0000x reference)
//
#include <hip/hip_runtime.h>
#include <math.h>
#include <stdint.h>

#define BB 1024
#define SS 200
#define HH 128
#define NI 100000

typedef __attribute__((ext_vector_type(8))) short short8;  // 8 bf16 (4 VGPRs)
typedef __attribute__((ext_vector_type(4))) float f32x4;   // MFMA C/D

// tanh(x) = sign(x) * (1 - e^{-2|x|}) / (1 + e^{-2|x|})
__device__ __forceinline__ float fast_tanh(float x) {
    float ax = fabsf(x);
    float t = __expf(-2.0f * ax);
    float r = (1.0f - t) / (1.0f + t);
    return copysignf(r, x);
}

// Split 8 consecutive fp32 into bf16 hi + bf16 lo (truncation split).
__device__ __forceinline__ void split8(const float* __restrict__ p,
                                       short8& hi, short8& lo) {
    const float4* p4 = reinterpret_cast<const float4*>(p);
    float4 x0 = p4[0], x1 = p4[1];
    float v[8] = {x0.x, x0.y, x0.z, x0.w, x1.x, x1.y, x1.z, x1.w};
    #pragma unroll
    for (int j = 0; j < 8; ++j) {
        unsigned u = __float_as_uint(v[j]);
        unsigned short h = (unsigned short)(u >> 16);
        hi[j] = (short)h;
        float r = v[j] - __uint_as_float(((unsigned)h) << 16);
        lo[j] = (short)(__float_as_uint(r) >> 16);
    }
}

// K1: even blocks compute att[b,:] -> ws ; odd blocks zero-fill one out row.
__global__ __launch_bounds__(256, 4)
void rrd_score_fill_kernel(const float* __restrict__ allm,      // [B,S,H]
                           const float* __restrict__ lastm,     // [B,H]
                           const unsigned char* __restrict__ mask, // [B,S]
                           const float* __restrict__ Ur,        // [H,H]
                           const float* __restrict__ Wr,        // [H,H]
                           const float* __restrict__ Vr,        // [1,H]
                           const float* __restrict__ Vrb,       // [1]
                           float* __restrict__ att_ws,          // [B,S]
                           float* __restrict__ out) {           // [B,N]
    const int tid = threadIdx.x;
    const int idx = blockIdx.x >> 1;

    if (blockIdx.x & 1) {
        // ---- fill role: zero out[idx, :] fire-and-forget (drain at kernel end,
        //      overlapped across 1024 independent blocks) ----
        float4* orow = reinterpret_cast<float4*>(out + (size_t)idx * NI);
        const float4 z4 = make_float4(0.f, 0.f, 0.f, 0.f);
        for (int i = tid; i < NI / 4; i += 256) orow[i] = z4;
        return;
    }

    const int b = idx;
    const int lane = tid & 63;
    const int w = tid >> 6;       // wave id: rows [64w, 64w+64)
    const int col = lane & 15;
    const int quad = lane >> 4;

    __shared__ float s_last[HH];
    __shared__ float s_lm[HH];
    __shared__ float s_vr[HH];
    __shared__ float s_score[256];
    __shared__ float s_red[8];

    if (tid < HH) s_last[tid] = lastm[b * HH + tid];
    else          s_vr[tid - HH] = Vr[tid - HH];
    __syncthreads();

    // ---- lm[k] = sum_h last[b,h] * Wr[k,h] ----
    if (tid < HH) {
        const float4* wrow = reinterpret_cast<const float4*>(Wr + tid * HH);
        const float4* lrow = reinterpret_cast<const float4*>(s_last);
        float4 acc = make_float4(0.f, 0.f, 0.f, 0.f);
        #pragma unroll
        for (int i = 0; i < HH / 4; ++i) {
            float4 wv = wrow[i];
            float4 lv = lrow[i];
            acc.x = fmaf(lv.x, wv.x, acc.x);
            acc.y = fmaf(lv.y, wv.y, acc.y);
            acc.z = fmaf(lv.z, wv.z, acc.z);
            acc.w = fmaf(lv.w, wv.w, acc.w);
        }
        s_lm[tid] = (acc.x + acc.y) + (acc.z + acc.w);
    }
    __syncthreads();

    // ---- MFMA: am[s,k] = A[s,:] . Ur[k,:], split-bf16 3-term ----
    const int row0 = w * 64;
    #pragma unroll 1
    for (int p = 0; p < 2; ++p) {
        f32x4 C[2][8] = {};
        #pragma unroll 1
        for (int c = 0; c < 4; ++c) {      // K chunks of 32
            short8 Bh[8], Bl[8];
            #pragma unroll
            for (int n = 0; n < 8; ++n) {
                const float* bp = Ur + (size_t)(n * 16 + col) * HH + c * 32 + quad * 8;
                split8(bp, Bh[n], Bl[n]);
            }
            #pragma unroll
            for (int t = 0; t < 2; ++t) {
                int row = row0 + (p * 2 + t) * 16 + col;
                if (row > SS - 1) row = SS - 1;
                const float* ap = allm + ((size_t)b * SS + row) * HH + c * 32 + quad * 8;
                short8 Ah, Al;
                split8(ap, Ah, Al);
                #pragma unroll
                for (int n = 0; n < 8; ++n) {
                    C[t][n] = __builtin_amdgcn_mfma_f32_16x16x32_bf16(Ah, Bh[n], C[t][n], 0, 0, 0);
                    C[t][n] = __builtin_amdgcn_mfma_f32_16x16x32_bf16(Ah, Bl[n], C[t][n], 0, 0, 0);
                    C[t][n] = __builtin_amdgcn_mfma_f32_16x16x32_bf16(Al, Bh[n], C[t][n], 0, 0, 0);
                }
            }
        }
        // ---- epilogue in C layout: col=lane&15, row=quad*4+reg ----
        #pragma unroll
        for (int t = 0; t < 2; ++t) {
            float a0 = 0.f, a1 = 0.f, a2 = 0.f, a3 = 0.f;
            #pragma unroll
            for (int n = 0; n < 8; ++n) {
                float lmc = s_lm[n * 16 + col];
                float vrc = s_vr[n * 16 + col];
                a0 = fmaf(vrc, fast_tanh(C[t][n][0] + lmc), a0);
                a1 = fmaf(vrc, fast_tanh(C[t][n][1] + lmc), a1);
                a2 = fmaf(vrc, fast_tanh(C[t][n][2] + lmc), a2);
                a3 = fmaf(vrc, fast_tanh(C[t][n][3] + lmc), a3);
            }
            #pragma unroll
            for (int off = 1; off < 16; off <<= 1) {
                a0 += __shfl_xor(a0, off, 64);
                a1 += __shfl_xor(a1, off, 64);
                a2 += __shfl_xor(a2, off, 64);
                a3 += __shfl_xor(a3, off, 64);
            }
            if (col == 0) {
                int rb = row0 + (p * 2 + t) * 16 + quad * 4;
                s_score[rb + 0] = a0;
                s_score[rb + 1] = a1;
                s_score[rb + 2] = a2;
                s_score[rb + 3] = a3;
            }
        }
    }
    __syncthreads();

    // ---- softmax over S; att -> workspace ----
    const int s = tid;
    float score = s_score[s] + Vrb[0];
    if (s < SS && mask[b * SS + s]) score = -1e9f;

    float v = (s < SS) ? score : -3.0e38f;
    #pragma unroll
    for (int off = 32; off > 0; off >>= 1)
        v = fmaxf(v, __shfl_down(v, off, 64));
    if (lane == 0) s_red[w] = v;
    __syncthreads();
    float m = fmaxf(fmaxf(s_red[0], s_red[1]), fmaxf(s_red[2], s_red[3]));

    float e = (s < SS) ? __expf(score - m) : 0.f;
    float sv = e;
    #pragma unroll
    for (int off = 32; off > 0; off >>= 1)
        sv += __shfl_down(sv, off, 64);
    if (lane == 0) s_red[4 + w] = sv;
    __syncthreads();
    float tot = (s_red[4] + s_red[5]) + (s_red[6] + s_red[7]);

    if (s < SS) att_ws[b * SS + s] = e / tot;
}

// K2: scatter att into the (now zeroed) output rows. Kernel boundary orders
// these atomics after ALL of K1's fill stores (device scope).
__global__ __launch_bounds__(256, 8)
void rrd_scatter_kernel(const float* __restrict__ att_ws,   // [B,S]
                        const int* __restrict__ item_seq,   // [B,S]
                        float* __restrict__ out) {          // [B,N]
    const int b = blockIdx.x;
    const int s = threadIdx.x;
    if (s < SS) {
        float att = att_ws[b * SS + s];
        int idx = item_seq[b * SS + s];
        atomicAdd(out + (size_t)b * NI + idx, att);
    }
}

extern "C" void kernel_launch(void* const* d_in, const int* in_sizes, int n_in,
                              void* d_out, int out_size, void* d_ws, size_t ws_size,
                              hipStream_t stream) {
    const float* allm   = (const float*)d_in[0];
    const float* lastm  = (const float*)d_in[1];
    const int*   iseq   = (const int*)d_in[2];
    const unsigned char* mask = (const unsigned char*)d_in[3];
    const float* Ur     = (const float*)d_in[4];
    const float* Wr     = (const float*)d_in[5];
    const float* Vr     = (const float*)d_in[6];
    const float* Vrb    = (const float*)d_in[7];
    float* out          = (float*)d_out;
    float* att_ws       = (float*)d_ws;     // 1024*200*4 = 800 KB

    rrd_score_fill_kernel<<<dim3(2 * BB), dim3(256), 0, stream>>>(
        allm, lastm, mask, Ur, Wr, Vr, Vrb, att_ws, out);
    rrd_scatter_kernel<<<dim3(BB), dim3(256), 0, stream>>>(
        att_ws, iseq, out);
}

// Round 7
// 678.094 us; speedup vs baseline: 1.0700x; 1.0700x over previous
//
#include <hip/hip_runtime.h>
#include <math.h>
#include <stdint.h>

#define BB 1024
#define SS 200
#define HH 128
#define NI 100000

typedef __attribute__((ext_vector_type(8))) short short8;  // 8 bf16 (4 VGPRs)
typedef __attribute__((ext_vector_type(4))) float f32x4;   // MFMA C/D

// tanh(x) = sign(x) * (1 - e^{-2|x|}) / (1 + e^{-2|x|})
__device__ __forceinline__ float fast_tanh(float x) {
    float ax = fabsf(x);
    float t = __expf(-2.0f * ax);
    float r = (1.0f - t) / (1.0f + t);
    return copysignf(r, x);
}

// Split 8 consecutive fp32 into bf16 hi + bf16 lo (truncation split).
__device__ __forceinline__ void split8(const float* __restrict__ p,
                                       short8& hi, short8& lo) {
    const float4* p4 = reinterpret_cast<const float4*>(p);
    float4 x0 = p4[0], x1 = p4[1];
    float v[8] = {x0.x, x0.y, x0.z, x0.w, x1.x, x1.y, x1.z, x1.w};
    #pragma unroll
    for (int j = 0; j < 8; ++j) {
        unsigned u = __float_as_uint(v[j]);
        unsigned short h = (unsigned short)(u >> 16);
        hi[j] = (short)h;
        float r = v[j] - __uint_as_float(((unsigned)h) << 16);
        lo[j] = (short)(__float_as_uint(r) >> 16);
    }
}

// K0: split Ur (fp32 [128][128]) into bf16 hi/lo planes in workspace.
__global__ __launch_bounds__(256, 4)
void rrd_prep_kernel(const float* __restrict__ Ur,
                     unsigned short* __restrict__ ur_hi,
                     unsigned short* __restrict__ ur_lo) {
    int i = blockIdx.x * 256 + threadIdx.x;   // grid 64 -> 16384 elements
    float v = Ur[i];
    unsigned u = __float_as_uint(v);
    unsigned short h = (unsigned short)(u >> 16);
    float r = v - __uint_as_float(((unsigned)h) << 16);
    ur_hi[i] = h;
    ur_lo[i] = (unsigned short)(__float_as_uint(r) >> 16);
}

// K1: compute att[b,:] -> ws (no fill, no scatter).
__global__ __launch_bounds__(256, 4)
void rrd_score_kernel(const float* __restrict__ allm,      // [B,S,H]
                      const float* __restrict__ lastm,     // [B,H]
                      const unsigned char* __restrict__ mask, // [B,S]
                      const unsigned short* __restrict__ ur_hi, // [H,H] bf16
                      const unsigned short* __restrict__ ur_lo, // [H,H] bf16
                      const float* __restrict__ Wr,        // [H,H]
                      const float* __restrict__ Vr,        // [1,H]
                      const float* __restrict__ Vrb,       // [1]
                      float* __restrict__ att_ws) {        // [B,S]
    const int b = blockIdx.x;
    const int tid = threadIdx.x;
    const int lane = tid & 63;
    const int w = tid >> 6;       // wave id: rows [64w, 64w+64)
    const int col = lane & 15;
    const int quad = lane >> 4;

    __shared__ float s_last[HH];
    __shared__ float s_lm[HH];
    __shared__ float s_vr[HH];
    __shared__ float s_score[256];
    __shared__ float s_red[8];

    if (tid < HH) s_last[tid] = lastm[b * HH + tid];
    else          s_vr[tid - HH] = Vr[tid - HH];
    __syncthreads();

    // ---- lm[k] = sum_h last[b,h] * Wr[k,h] ----
    if (tid < HH) {
        const float4* wrow = reinterpret_cast<const float4*>(Wr + tid * HH);
        const float4* lrow = reinterpret_cast<const float4*>(s_last);
        float4 acc = make_float4(0.f, 0.f, 0.f, 0.f);
        #pragma unroll
        for (int i = 0; i < HH / 4; ++i) {
            float4 wv = wrow[i];
            float4 lv = lrow[i];
            acc.x = fmaf(lv.x, wv.x, acc.x);
            acc.y = fmaf(lv.y, wv.y, acc.y);
            acc.z = fmaf(lv.z, wv.z, acc.z);
            acc.w = fmaf(lv.w, wv.w, acc.w);
        }
        s_lm[tid] = (acc.x + acc.y) + (acc.z + acc.w);
    }
    __syncthreads();

    // ---- MFMA: am[s,k] = A[s,:] . Ur[k,:], split-bf16 3-term ----
    const int row0 = w * 64;
    #pragma unroll 1
    for (int p = 0; p < 2; ++p) {
        f32x4 C[2][8] = {};
        #pragma unroll 1
        for (int c = 0; c < 4; ++c) {      // K chunks of 32
            short8 Bh[8], Bl[8];
            #pragma unroll
            for (int n = 0; n < 8; ++n) {  // direct 16B bf16 loads, no split VALU
                const size_t off = (size_t)(n * 16 + col) * HH + c * 32 + quad * 8;
                Bh[n] = *reinterpret_cast<const short8*>(ur_hi + off);
                Bl[n] = *reinterpret_cast<const short8*>(ur_lo + off);
            }
            #pragma unroll
            for (int t = 0; t < 2; ++t) {
                int row = row0 + (p * 2 + t) * 16 + col;
                if (row > SS - 1) row = SS - 1;
                const float* ap = allm + ((size_t)b * SS + row) * HH + c * 32 + quad * 8;
                short8 Ah, Al;
                split8(ap, Ah, Al);
                #pragma unroll
                for (int n = 0; n < 8; ++n) {
                    C[t][n] = __builtin_amdgcn_mfma_f32_16x16x32_bf16(Ah, Bh[n], C[t][n], 0, 0, 0);
                    C[t][n] = __builtin_amdgcn_mfma_f32_16x16x32_bf16(Ah, Bl[n], C[t][n], 0, 0, 0);
                    C[t][n] = __builtin_amdgcn_mfma_f32_16x16x32_bf16(Al, Bh[n], C[t][n], 0, 0, 0);
                }
            }
        }
        // ---- epilogue in C layout: col=lane&15, row=quad*4+reg ----
        #pragma unroll
        for (int t = 0; t < 2; ++t) {
            float a0 = 0.f, a1 = 0.f, a2 = 0.f, a3 = 0.f;
            #pragma unroll
            for (int n = 0; n < 8; ++n) {
                float lmc = s_lm[n * 16 + col];
                float vrc = s_vr[n * 16 + col];
                a0 = fmaf(vrc, fast_tanh(C[t][n][0] + lmc), a0);
                a1 = fmaf(vrc, fast_tanh(C[t][n][1] + lmc), a1);
                a2 = fmaf(vrc, fast_tanh(C[t][n][2] + lmc), a2);
                a3 = fmaf(vrc, fast_tanh(C[t][n][3] + lmc), a3);
            }
            #pragma unroll
            for (int off = 1; off < 16; off <<= 1) {
                a0 += __shfl_xor(a0, off, 64);
                a1 += __shfl_xor(a1, off, 64);
                a2 += __shfl_xor(a2, off, 64);
                a3 += __shfl_xor(a3, off, 64);
            }
            if (col == 0) {
                int rb = row0 + (p * 2 + t) * 16 + quad * 4;
                s_score[rb + 0] = a0;
                s_score[rb + 1] = a1;
                s_score[rb + 2] = a2;
                s_score[rb + 3] = a3;
            }
        }
    }
    __syncthreads();

    // ---- softmax over S; att -> workspace ----
    const int s = tid;
    float score = s_score[s] + Vrb[0];
    if (s < SS && mask[b * SS + s]) score = -1e9f;

    float v = (s < SS) ? score : -3.0e38f;
    #pragma unroll
    for (int off = 32; off > 0; off >>= 1)
        v = fmaxf(v, __shfl_down(v, off, 64));
    if (lane == 0) s_red[w] = v;
    __syncthreads();
    float m = fmaxf(fmaxf(s_red[0], s_red[1]), fmaxf(s_red[2], s_red[3]));

    float e = (s < SS) ? __expf(score - m) : 0.f;
    float sv = e;
    #pragma unroll
    for (int off = 32; off > 0; off >>= 1)
        sv += __shfl_down(sv, off, 64);
    if (lane == 0) s_red[4 + w] = sv;
    __syncthreads();
    float tot = (s_red[4] + s_red[5]) + (s_red[6] + s_red[7]);

    if (s < SS) att_ws[b * SS + s] = e / tot;
}

// K2: flat contiguous zero of out (fillBufferAligned pattern: grid-stride
// float4 stores, fully aligned, no barriers -> ~6.2 TB/s).
__global__ __launch_bounds__(256, 8)
void rrd_fill_kernel(float4* __restrict__ out4) {
    const size_t total = (size_t)BB * NI / 4;   // 25,600,000 float4
    size_t i = (size_t)blockIdx.x * 256 + threadIdx.x;
    const size_t stride = (size_t)gridDim.x * 256;
    const float4 z4 = make_float4(0.f, 0.f, 0.f, 0.f);
    for (; i < total; i += stride) out4[i] = z4;
}

// K3: scatter att into the zeroed output rows. Kernel boundary orders these
// atomics after ALL fill stores (device scope).
__global__ __launch_bounds__(256, 8)
void rrd_scatter_kernel(const float* __restrict__ att_ws,   // [B,S]
                        const int* __restrict__ item_seq,   // [B,S]
                        float* __restrict__ out) {          // [B,N]
    const int b = blockIdx.x;
    const int s = threadIdx.x;
    if (s < SS) {
        float att = att_ws[b * SS + s];
        int idx = item_seq[b * SS + s];
        atomicAdd(out + (size_t)b * NI + idx, att);
    }
}

extern "C" void kernel_launch(void* const* d_in, const int* in_sizes, int n_in,
                              void* d_out, int out_size, void* d_ws, size_t ws_size,
                              hipStream_t stream) {
    const float* allm   = (const float*)d_in[0];
    const float* lastm  = (const float*)d_in[1];
    const int*   iseq   = (const int*)d_in[2];
    const unsigned char* mask = (const unsigned char*)d_in[3];
    const float* Ur     = (const float*)d_in[4];
    const float* Wr     = (const float*)d_in[5];
    const float* Vr     = (const float*)d_in[6];
    const float* Vrb    = (const float*)d_in[7];
    float* out          = (float*)d_out;

    // workspace layout: [Ur_hi 32KB][Ur_lo 32KB][att 800KB]
    unsigned short* ur_hi = (unsigned short*)d_ws;
    unsigned short* ur_lo = ur_hi + HH * HH;
    float* att_ws = (float*)((char*)d_ws + 2 * HH * HH * sizeof(unsigned short));

    rrd_prep_kernel<<<dim3(HH * HH / 256), dim3(256), 0, stream>>>(Ur, ur_hi, ur_lo);
    rrd_score_kernel<<<dim3(BB), dim3(256), 0, stream>>>(
        allm, lastm, mask, ur_hi, ur_lo, Wr, Vr, Vrb, att_ws);
    rrd_fill_kernel<<<dim3(4096), dim3(256), 0, stream>>>(
        reinterpret_cast<float4*>(out));
    rrd_scatter_kernel<<<dim3(BB), dim3(256), 0, stream>>>(
        att_ws, iseq, out);
}